// Round 1
// baseline (749.207 us; speedup 1.0000x reference)
//
#include <hip/hip_runtime.h>

// Problem: msg[e] = src_emb[src_idx[e]] * e_att[e]; out = segment_sum(msg, dst_idx, N_DST)
// Shapes: src_emb [50000,64] f32, e_att [800000,1] f32, src_idx/dst_idx [800000] i32
// out [50000,64] f32.

#define D 64

__global__ void __launch_bounds__(256)
scatter_mul_sum_kernel(const float* __restrict__ src_emb,
                       const float* __restrict__ e_att,
                       const int*   __restrict__ src_idx,
                       const int*   __restrict__ dst_idx,
                       float*       __restrict__ out,
                       int E) {
    int tid  = blockIdx.x * blockDim.x + threadIdx.x;
    int e    = tid >> 4;   // 16 threads cooperate on one edge (64 floats = 16 x float4)
    int part = tid & 15;   // which float4 of the 256B row
    if (e >= E) return;

    int   s = src_idx[e];
    int   d = dst_idx[e];
    float a = e_att[e];

    const float4* srow = (const float4*)(src_emb + (size_t)s * D);
    float4 v = srow[part];   // coalesced: 16 consecutive threads read 16 consecutive float4s

    float* orow = out + (size_t)d * D + part * 4;
    atomicAdd(orow + 0, v.x * a);
    atomicAdd(orow + 1, v.y * a);
    atomicAdd(orow + 2, v.z * a);
    atomicAdd(orow + 3, v.w * a);
}

extern "C" void kernel_launch(void* const* d_in, const int* in_sizes, int n_in,
                              void* d_out, int out_size, void* d_ws, size_t ws_size,
                              hipStream_t stream) {
    const float* src_emb = (const float*)d_in[0];
    const float* e_att   = (const float*)d_in[1];
    const int*   src_idx = (const int*)d_in[2];
    const int*   dst_idx = (const int*)d_in[3];
    float*       out     = (float*)d_out;

    const int E = in_sizes[2];   // 800000

    // Harness poisons d_out with 0xAA before every timed launch — zero it.
    hipMemsetAsync(d_out, 0, (size_t)out_size * sizeof(float), stream);

    const int threads = 256;                 // 16 edges per block
    const int total   = E * 16;              // 16 threads per edge
    const int blocks  = (total + threads - 1) / threads;
    scatter_mul_sum_kernel<<<blocks, threads, 0, stream>>>(
        src_emb, e_att, src_idx, dst_idx, out, E);
}

// Round 2
// 209.586 us; speedup vs baseline: 3.5747x; 3.5747x over previous
//
#include <hip/hip_runtime.h>

// msg[e] = src_emb[src_idx[e]] * e_att[e]; out = segment_sum(msg, dst_idx, N_DST)
// src_emb [50000,64] f32, e_att [800000,1] f32, src_idx/dst_idx [800000] i32,
// out [50000,64] f32.
//
// Two-phase: build CSR (counts -> exclusive scan -> scatter edge ids), then
// atomic-free gather-sum: one wave (64 lanes) per dst row; 4 sub-groups of 16
// lanes process every-4th edge with float4 row loads; shuffle-combine.

#define D 64

__global__ void __launch_bounds__(256)
hist_kernel(const int* __restrict__ dst_idx, int* __restrict__ counts, int E) {
    int e = blockIdx.x * blockDim.x + threadIdx.x;
    if (e < E) atomicAdd(&counts[dst_idx[e]], 1);
}

__global__ void __launch_bounds__(256)
block_reduce_kernel(const int* __restrict__ counts, int* __restrict__ blocksums, int n) {
    __shared__ int lds[256];
    int i = blockIdx.x * 256 + threadIdx.x;
    lds[threadIdx.x] = (i < n) ? counts[i] : 0;
    __syncthreads();
    for (int s = 128; s > 0; s >>= 1) {
        if (threadIdx.x < s) lds[threadIdx.x] += lds[threadIdx.x + s];
        __syncthreads();
    }
    if (threadIdx.x == 0) blocksums[blockIdx.x] = lds[0];
}

// single block; nb <= 256 (nb = 196 here)
__global__ void __launch_bounds__(256)
scan_blocksums_kernel(int* __restrict__ blocksums, int nb) {
    __shared__ int lds[256];
    int t = threadIdx.x;
    int v = (t < nb) ? blocksums[t] : 0;
    lds[t] = v;
    __syncthreads();
    for (int off = 1; off < 256; off <<= 1) {
        int x = (t >= off) ? lds[t - off] : 0;
        __syncthreads();
        lds[t] += x;
        __syncthreads();
    }
    if (t < nb) blocksums[t] = lds[t] - v;   // exclusive
}

__global__ void __launch_bounds__(256)
scan_final_kernel(const int* __restrict__ counts, const int* __restrict__ blocksums,
                  int* __restrict__ offsets, int* __restrict__ cursor, int n) {
    __shared__ int lds[256];
    int t = threadIdx.x;
    int i = blockIdx.x * 256 + t;
    int v = (i < n) ? counts[i] : 0;
    lds[t] = v;
    __syncthreads();
    for (int off = 1; off < 256; off <<= 1) {
        int x = (t >= off) ? lds[t - off] : 0;
        __syncthreads();
        lds[t] += x;
        __syncthreads();
    }
    int excl = lds[t] - v + blocksums[blockIdx.x];
    if (i < n) { offsets[i] = excl; cursor[i] = excl; }
}

__global__ void __launch_bounds__(256)
scatter_ids_kernel(const int* __restrict__ dst_idx, int* __restrict__ cursor,
                   int* __restrict__ edge_ids, int E) {
    int e = blockIdx.x * blockDim.x + threadIdx.x;
    if (e < E) {
        int p = atomicAdd(&cursor[dst_idx[e]], 1);
        edge_ids[p] = e;
    }
}

// One wave per dst row. lane = sub*16 + part: sub (0..3) strides edges,
// part (0..15) owns one float4 of the 64-float row.
__global__ void __launch_bounds__(256)
gather_kernel(const float* __restrict__ src_emb, const float* __restrict__ e_att,
              const int* __restrict__ src_idx, const int* __restrict__ edge_ids,
              const int* __restrict__ offsets, const int* __restrict__ counts,
              float* __restrict__ out, int n_dst) {
    int wave = (blockIdx.x * blockDim.x + threadIdx.x) >> 6;
    if (wave >= n_dst) return;
    int lane = threadIdx.x & 63;
    int part = lane & 15;
    int sub  = lane >> 4;

    int start = offsets[wave];
    int cnt   = counts[wave];
    int end   = start + cnt;

    float4 acc = make_float4(0.f, 0.f, 0.f, 0.f);
    for (int p = start + sub; p < end; p += 4) {
        int   e = edge_ids[p];
        int   s = src_idx[e];
        float a = e_att[e];
        float4 v = ((const float4*)src_emb)[(size_t)s * 16 + part];
        acc.x = fmaf(v.x, a, acc.x);
        acc.y = fmaf(v.y, a, acc.y);
        acc.z = fmaf(v.z, a, acc.z);
        acc.w = fmaf(v.w, a, acc.w);
    }
    // combine the 4 sub-groups: lanes 0..15 <- +32, then +16
    acc.x += __shfl_down(acc.x, 32); acc.y += __shfl_down(acc.y, 32);
    acc.z += __shfl_down(acc.z, 32); acc.w += __shfl_down(acc.w, 32);
    acc.x += __shfl_down(acc.x, 16); acc.y += __shfl_down(acc.y, 16);
    acc.z += __shfl_down(acc.z, 16); acc.w += __shfl_down(acc.w, 16);

    if (sub == 0) {
        ((float4*)out)[(size_t)wave * 16 + part] = acc;
    }
}

extern "C" void kernel_launch(void* const* d_in, const int* in_sizes, int n_in,
                              void* d_out, int out_size, void* d_ws, size_t ws_size,
                              hipStream_t stream) {
    const float* src_emb = (const float*)d_in[0];
    const float* e_att   = (const float*)d_in[1];
    const int*   src_idx = (const int*)d_in[2];
    const int*   dst_idx = (const int*)d_in[3];
    float*       out     = (float*)d_out;

    const int E     = in_sizes[2];       // 800000
    const int n_dst = out_size / D;      // 50000

    // ws layout (ints): counts | offsets | cursor | blocksums(256) | edge_ids
    int* ws        = (int*)d_ws;
    int* counts    = ws;
    int* offsets   = ws + n_dst;
    int* cursor    = ws + 2 * n_dst;
    int* blocksums = ws + 3 * n_dst;
    int* edge_ids  = ws + 3 * n_dst + 256;

    hipMemsetAsync(counts, 0, (size_t)n_dst * sizeof(int), stream);

    const int nb = (n_dst + 255) / 256;          // 196 scan blocks (<=256 required)
    const int eb = (E + 255) / 256;              // edge-parallel blocks

    hist_kernel<<<eb, 256, 0, stream>>>(dst_idx, counts, E);
    block_reduce_kernel<<<nb, 256, 0, stream>>>(counts, blocksums, n_dst);
    scan_blocksums_kernel<<<1, 256, 0, stream>>>(blocksums, nb);
    scan_final_kernel<<<nb, 256, 0, stream>>>(counts, blocksums, offsets, cursor, n_dst);
    scatter_ids_kernel<<<eb, 256, 0, stream>>>(dst_idx, cursor, edge_ids, E);

    // 4 dst rows per 256-thread block (one wave each)
    const int gb = (n_dst + 3) / 4;
    gather_kernel<<<gb, 256, 0, stream>>>(src_emb, e_att, src_idx, edge_ids,
                                          offsets, counts, out, n_dst);
}